// Round 7
// baseline (136.541 us; speedup 1.0000x reference)
//
#include <hip/hip_runtime.h>

typedef _Float16 f16;
typedef _Float16 f16x8 __attribute__((ext_vector_type(8)));
typedef _Float16 f16x4 __attribute__((ext_vector_type(4)));
typedef _Float16 f16x2 __attribute__((ext_vector_type(2)));
typedef float f32x4 __attribute__((ext_vector_type(4)));
typedef float f32x16 __attribute__((ext_vector_type(16)));
typedef unsigned int u32x2 __attribute__((ext_vector_type(2)));

#define S_TOK 4096
#define NB 2
#define NH 8
#define DKH 64
#define DMODEL 512

static __device__ __forceinline__ f32x4 mfma16(f16x8 a, f16x8 b, f32x4 c) {
    return __builtin_amdgcn_mfma_f32_16x16x32_f16(a, b, c, 0, 0, 0);
}
static __device__ __forceinline__ f32x16 mfma32(f16x8 a, f16x8 b, f32x16 c) {
    return __builtin_amdgcn_mfma_f32_32x32x16_f16(a, b, c, 0, 0, 0);
}
// async global->LDS, 16B per lane; lds must be wave-uniform base
static __device__ __forceinline__ void gl16(const f16* g, f16* l) {
    __builtin_amdgcn_global_load_lds(
        (const __attribute__((address_space(1))) unsigned int*)g,
        (__attribute__((address_space(3))) unsigned int*)l, 16, 0, 0);
}

// ---------------- fused QKV projection: out = x @ W^T (x:[8192][512] f32, W:[512][512] f32)
// mode 0 = Q (scaled 1/8 * log2(e), [bh][s][dk]); 1 = K; 2 = V ([bh][dk][s] transposed)
__global__ __launch_bounds__(256)
void proj_fused_kernel(const float* __restrict__ qx, const float* __restrict__ kx,
                       const float* __restrict__ vx,
                       const float* __restrict__ Wqp, const float* __restrict__ Wkp,
                       const float* __restrict__ Wvp,
                       f16* __restrict__ qo, f16* __restrict__ ko, f16* __restrict__ vo)
{
    const int mode = blockIdx.z;
    const float* x = (mode == 0) ? qx : (mode == 1) ? kx : vx;
    const float* W = (mode == 0) ? Wqp : (mode == 1) ? Wkp : Wvp;
    f16* out = (mode == 0) ? qo : (mode == 1) ? ko : vo;

    __shared__ f16 As[128 * 40];
    __shared__ f16 Bs[128 * 40];
    const int m0 = blockIdx.x * 128;
    const int n0 = blockIdx.y * 128;
    const int tid = threadIdx.x;
    const int wv = tid >> 6;
    const int lane = tid & 63;
    const int lr = lane & 15, lg = lane >> 4;
    const int wm = (wv >> 1) * 64, wn = (wv & 1) * 64;

    f32x4 acc[4][4];
#pragma unroll
    for (int i = 0; i < 4; ++i)
#pragma unroll
        for (int j = 0; j < 4; ++j) acc[i][j] = f32x4{0.f, 0.f, 0.f, 0.f};

    for (int kb = 0; kb < DMODEL; kb += 32) {
#pragma unroll
        for (int c = 0; c < 2; ++c) {
            const int chunk = tid + c * 256;
            const int row = chunk >> 2;
            const int col = (chunk & 3) * 8;
            const float* ga = x + (size_t)(m0 + row) * DMODEL + kb + col;
            float4 a0 = *(const float4*)ga;
            float4 a1 = *(const float4*)(ga + 4);
            f16x8 ha = { (f16)a0.x, (f16)a0.y, (f16)a0.z, (f16)a0.w,
                         (f16)a1.x, (f16)a1.y, (f16)a1.z, (f16)a1.w };
            *(f16x8*)(As + row * 40 + col) = ha;
            const float* gb = W + (size_t)(n0 + row) * DMODEL + kb + col;
            float4 b0 = *(const float4*)gb;
            float4 b1 = *(const float4*)(gb + 4);
            f16x8 hb = { (f16)b0.x, (f16)b0.y, (f16)b0.z, (f16)b0.w,
                         (f16)b1.x, (f16)b1.y, (f16)b1.z, (f16)b1.w };
            *(f16x8*)(Bs + row * 40 + col) = hb;
        }
        __syncthreads();
        f16x8 af[4], bf[4];
#pragma unroll
        for (int i = 0; i < 4; ++i)
            af[i] = *(const f16x8*)(As + (wm + 16 * i + lr) * 40 + 8 * lg);
#pragma unroll
        for (int j = 0; j < 4; ++j)
            bf[j] = *(const f16x8*)(Bs + (wn + 16 * j + lr) * 40 + 8 * lg);
#pragma unroll
        for (int i = 0; i < 4; ++i)
#pragma unroll
            for (int j = 0; j < 4; ++j)
                acc[i][j] = mfma16(af[i], bf[j], acc[i][j]);
        __syncthreads();
    }

#pragma unroll
    for (int i = 0; i < 4; ++i) {
        const int mbase = m0 + wm + 16 * i + 4 * lg;
#pragma unroll
        for (int j = 0; j < 4; ++j) {
            const int n = n0 + wn + 16 * j + lr;
            const int h = n >> 6, dk = n & 63;
            if (mode == 2) {
                const int b = mbase >> 12;
                const int s = mbase & 4095;
                f16x4 v4;
#pragma unroll
                for (int r = 0; r < 4; ++r) v4[r] = (f16)acc[i][j][r];
                *(f16x4*)(out + ((size_t)(b * NH + h) * DKH + dk) * S_TOK + s) = v4;
            } else {
                const float sc = (mode == 0) ? 0.1803368801111244f : 1.0f;
#pragma unroll
                for (int r = 0; r < 4; ++r) {
                    const int m = mbase + r;
                    const int b = m >> 12, s = m & 4095;
                    out[((size_t)(b * NH + h) * S_TOK + s) * DKH + dk] = (f16)(acc[i][j][r] * sc);
                }
            }
        }
    }
}

// ---------------- causal flash attention, 32x32 MFMA, 4 kv-chunks, permlane P exchange
// 1024 blocks x 4 waves (32 q/wave, QBLK=128). Block (j, cb): (qt=j, chunk cb) then
// (qt=31-j, chunk 3-cb) -> 16-17 steps every block. No P LDS (permlane32_swap).
__global__ __launch_bounds__(256, 4)
void attn_kernel(const f16* __restrict__ qh, const f16* __restrict__ kh,
                 const f16* __restrict__ vt, f16* __restrict__ pO, float* __restrict__ pL)
{
    __shared__ f16 Ks[2][64 * 64];   // [kv][dk], granule-XOR swizzled (slot = g ^ (row&7))
    __shared__ f16 Vs[2][64 * 64];   // [dk][kv], granule-XOR swizzled

    const int bid = blockIdx.x;
    const int bh = 2 * (bid & 7) + ((bid >> 3) & 1);   // XCD affinity: 2 heads/XCD
    const int j = (bid >> 4) & 31;
    const int cb = (bid >> 9) & 1;
    const int tid = threadIdx.x, wv = tid >> 6, lane = tid & 63;
    const int l31 = lane & 31, h = lane >> 5;

    const f16* Qp = qh + (size_t)bh * S_TOK * DKH;
    const f16* Kp = kh + (size_t)bh * S_TOK * DKH;
    const f16* Vp = vt + (size_t)bh * DKH * S_TOK;

    // staging: granule gid = tid (rows 0-31) and tid+256 (rows 32-63); slot = tid&7
    const int srow = tid >> 3;            // 0..31
    const int sg = tid & 7;
    const int sgx = sg ^ (srow & 7);      // pre-swizzled global granule (rows +32: same row&7)

    int cur = 0;
    for (int seg = 0; seg < 2; ++seg) {
        const int qt = seg ? (31 - j) : j;
        const int cc = seg ? (3 - cb) : cb;
        const int T = 2 * qt + 2;
        const int tb = (cc * T) >> 2;
        const int te = ((cc + 1) * T) >> 2;
        const int qw = qt * 128 + 32 * wv + l31;
        const int unit = (bh * 32 + qt) * 4 + cc;

        f16x8 aq[4];
#pragma unroll
        for (int s = 0; s < 4; ++s)
            aq[s] = *(const f16x8*)(Qp + (size_t)qw * DKH + 16 * s + 8 * h);

        f32x16 accO0 = {}, accO1 = {};
        float mrow = -1e20f, lrow = 0.f;

        if (te > tb) {
            {   // stage first tile into buf[cur]
                const f16* kp1 = Kp + (size_t)(64 * tb + srow) * DKH + sgx * 8;
                gl16(kp1, &Ks[cur][wv * 512]);
                gl16(kp1 + 32 * DKH, &Ks[cur][2048 + wv * 512]);
                const f16* vp1 = Vp + (size_t)srow * S_TOK + 64 * tb + sgx * 8;
                gl16(vp1, &Vs[cur][wv * 512]);
                gl16(vp1 + (size_t)32 * S_TOK, &Vs[cur][2048 + wv * 512]);
            }
            for (int t = tb; t < te; ++t) {
                __syncthreads();      // stage(t) landed; prior reads of buf[cur^1] done
                if (t + 1 < te) {     // stage next tile into the other buffer
                    const f16* kp1 = Kp + (size_t)(64 * (t + 1) + srow) * DKH + sgx * 8;
                    gl16(kp1, &Ks[cur ^ 1][wv * 512]);
                    gl16(kp1 + 32 * DKH, &Ks[cur ^ 1][2048 + wv * 512]);
                    const f16* vp1 = Vp + (size_t)srow * S_TOK + 64 * (t + 1) + sgx * 8;
                    gl16(vp1, &Vs[cur ^ 1][wv * 512]);
                    gl16(vp1 + (size_t)32 * S_TOK, &Vs[cur ^ 1][2048 + wv * 512]);
                }
                const f16* Kb = &Ks[cur][0];
                const f16* Vb = &Vs[cur][0];

                // S^T = K x Q^T : D[kv = 32*half + (e&3)+8*(e>>2)+4h][q = l31]
                f32x16 accS0 = {}, accS1 = {};
                __builtin_amdgcn_s_setprio(1);
#pragma unroll
                for (int s = 0; s < 4; ++s) {
                    f16x8 ak0 = *(const f16x8*)(Kb + l31 * 64 + ((2 * s + h) ^ (l31 & 7)) * 8);
                    f16x8 ak1 = *(const f16x8*)(Kb + (32 + l31) * 64 + ((2 * s + h) ^ (l31 & 7)) * 8);
                    accS0 = mfma32(ak0, aq[s], accS0);
                    accS1 = mfma32(ak1, aq[s], accS1);
                }
                __builtin_amdgcn_s_setprio(0);

                if (t >= 2 * qt) {   // diagonal tiles: causal mask
#pragma unroll
                    for (int e = 0; e < 16; ++e) {
                        const int kvb = 64 * t + (e & 3) + 8 * (e >> 2) + 4 * h;
                        accS0[e] = (kvb > qw) ? -1e30f : accS0[e];
                        accS1[e] = (kvb + 32 > qw) ? -1e30f : accS1[e];
                    }
                }

                // online softmax: 32 kv in-lane + xor-32 partner
                float tm = -1e30f;
#pragma unroll
                for (int e = 0; e < 16; ++e) tm = fmaxf(tm, fmaxf(accS0[e], accS1[e]));
                tm = fmaxf(tm, __shfl_xor(tm, 32));
                if (!__all(tm <= mrow + 8.f)) {   // defer-max (T13)
                    const float mn = fmaxf(mrow, tm);
                    const float sf = exp2f(mrow - mn);
                    lrow *= sf;
                    accO0 *= sf;  accO1 *= sf;
                    mrow = mn;
                }

                float ts = 0.f;
                // half 0 (kv 0..31): exp -> pack -> permlane -> PV s'=0,1
                {
                    unsigned int Xd0[4], Xd1[4];
#pragma unroll
                    for (int g = 0; g < 4; ++g) {
                        float p0 = exp2f(accS0[4 * g + 0] - mrow);
                        float p1 = exp2f(accS0[4 * g + 1] - mrow);
                        float p2 = exp2f(accS0[4 * g + 2] - mrow);
                        float p3 = exp2f(accS0[4 * g + 3] - mrow);
                        ts += (p0 + p1) + (p2 + p3);
                        union { f16x2 hh; unsigned int u; } a0, a1;
                        a0.hh = f16x2{(f16)p0, (f16)p1};
                        a1.hh = f16x2{(f16)p2, (f16)p3};
                        Xd0[g] = a0.u;  Xd1[g] = a1.u;
                    }
                    __builtin_amdgcn_s_setprio(1);
#pragma unroll
                    for (int sp = 0; sp < 2; ++sp) {
                        u32x2 rA = __builtin_amdgcn_permlane32_swap(Xd0[2 * sp], Xd0[2 * sp + 1], false, false);
                        u32x2 rB = __builtin_amdgcn_permlane32_swap(Xd1[2 * sp], Xd1[2 * sp + 1], false, false);
                        union { unsigned int u[4]; f16x8 v; } F;
                        F.u[0] = rA[0]; F.u[1] = rB[0]; F.u[2] = rA[1]; F.u[3] = rB[1];
                        f16x8 av0 = *(const f16x8*)(Vb + l31 * 64 + ((2 * sp + h) ^ (l31 & 7)) * 8);
                        f16x8 av1 = *(const f16x8*)(Vb + (32 + l31) * 64 + ((2 * sp + h) ^ (l31 & 7)) * 8);
                        accO0 = mfma32(av0, F.v, accO0);
                        accO1 = mfma32(av1, F.v, accO1);
                    }
                    __builtin_amdgcn_s_setprio(0);
                }
                // half 1 (kv 32..63): s'=2,3
                {
                    unsigned int Xd0[4], Xd1[4];
#pragma unroll
                    for (int g = 0; g < 4; ++g) {
                        float p0 = exp2f(accS1[4 * g + 0] - mrow);
                        float p1 = exp2f(accS1[4 * g + 1] - mrow);
                        float p2 = exp2f(accS1[4 * g + 2] - mrow);
                        float p3 = exp2f(accS1[4 * g + 3] - mrow);
                        ts += (p0 + p1) + (p2 + p3);
                        union { f16x2 hh; unsigned int u; } a0, a1;
                        a0.hh = f16x2{(f16)p0, (f16)p1};
                        a1.hh = f16x2{(f16)p2, (f16)p3};
                        Xd0[g] = a0.u;  Xd1[g] = a1.u;
                    }
                    __builtin_amdgcn_s_setprio(1);
#pragma unroll
                    for (int sp = 0; sp < 2; ++sp) {
                        const int spp = 2 + sp;
                        u32x2 rA = __builtin_amdgcn_permlane32_swap(Xd0[2 * sp], Xd0[2 * sp + 1], false, false);
                        u32x2 rB = __builtin_amdgcn_permlane32_swap(Xd1[2 * sp], Xd1[2 * sp + 1], false, false);
                        union { unsigned int u[4]; f16x8 v; } F;
                        F.u[0] = rA[0]; F.u[1] = rB[0]; F.u[2] = rA[1]; F.u[3] = rB[1];
                        f16x8 av0 = *(const f16x8*)(Vb + l31 * 64 + ((2 * spp + h) ^ (l31 & 7)) * 8);
                        f16x8 av1 = *(const f16x8*)(Vb + (32 + l31) * 64 + ((2 * spp + h) ^ (l31 & 7)) * 8);
                        accO0 = mfma32(av0, F.v, accO0);
                        accO1 = mfma32(av1, F.v, accO1);
                    }
                    __builtin_amdgcn_s_setprio(0);
                }
                ts += __shfl_xor(ts, 32);
                lrow += ts;
                cur ^= 1;
            }
        }

        // write partial: O_norm f16 + L = m + log2(l)
        const float invl = (lrow > 0.f) ? (1.f / lrow) : 0.f;
        f16* Ob = pO + ((size_t)unit * 128 + (32 * wv + l31)) * DKH;
#pragma unroll
        for (int g = 0; g < 4; ++g) {
            f16x4 o0, o1;
#pragma unroll
            for (int r = 0; r < 4; ++r) {
                o0[r] = (f16)(accO0[4 * g + r] * invl);
                o1[r] = (f16)(accO1[4 * g + r] * invl);
            }
            *(f16x4*)(Ob + 8 * g + 4 * h) = o0;
            *(f16x4*)(Ob + 32 + 8 * g + 4 * h) = o1;
        }
        if (h == 0)
            pL[unit * 128 + 32 * wv + l31] =
                (lrow > 0.f) ? (mrow + __log2f(lrow)) : -1e30f;
    }
}

// ---------------- merge 4 kv-chunk partials per q-row -> ctx f16
__global__ __launch_bounds__(256)
void merge_kernel(const f16* __restrict__ pO, const float* __restrict__ pL,
                  f16* __restrict__ ctx)
{
    const int tid = threadIdx.x;
    const int R = blockIdx.x * 32 + (tid >> 3);   // row id 0..65535
    const int dkg = tid & 7;
    const int bh = R >> 12, q = R & 4095;
    const int qt = q >> 7, qi = q & 127;
    const int ub = (bh * 32 + qt) * 4;

    float L[4];
#pragma unroll
    for (int c = 0; c < 4; ++c) L[c] = pL[(ub + c) * 128 + qi];
    float Lm = fmaxf(fmaxf(L[0], L[1]), fmaxf(L[2], L[3]));
    float w[4], wsum = 0.f;
#pragma unroll
    for (int c = 0; c < 4; ++c) { w[c] = exp2f(L[c] - Lm); wsum += w[c]; }
    const float inv = 1.f / wsum;

    float o[8];
#pragma unroll
    for (int i = 0; i < 8; ++i) o[i] = 0.f;
#pragma unroll
    for (int c = 0; c < 4; ++c) {
        f16x8 a = *(const f16x8*)(pO + ((size_t)(ub + c) * 128 + qi) * DKH + dkg * 8);
#pragma unroll
        for (int i = 0; i < 8; ++i) o[i] += w[c] * (float)a[i];
    }
    f16x8 ov;
#pragma unroll
    for (int i = 0; i < 8; ++i) ov[i] = (f16)(o[i] * inv);

    const int bb = bh >> 3, hh = bh & 7;
    *(f16x8*)(ctx + ((size_t)(bb * S_TOK + q)) * DMODEL + hh * DKH + dkg * 8) = ov;
}

// ---------------- output projection: out = ctx(f16) @ W_o^T + b_o, fp32 out
__global__ __launch_bounds__(256)
void oproj_kernel(const f16* __restrict__ A, const float* __restrict__ W,
                  const float* __restrict__ bias, float* __restrict__ out)
{
    __shared__ f16 As[128 * 40];
    __shared__ f16 Bs[128 * 40];
    const int m0 = blockIdx.x * 128;
    const int n0 = blockIdx.y * 128;
    const int tid = threadIdx.x;
    const int wv = tid >> 6;
    const int lane = tid & 63;
    const int lr = lane & 15, lg = lane >> 4;
    const int wm = (wv >> 1) * 64, wn = (wv & 1) * 64;

    f32x4 acc[4][4];
#pragma unroll
    for (int i = 0; i < 4; ++i)
#pragma unroll
        for (int j = 0; j < 4; ++j) acc[i][j] = f32x4{0.f, 0.f, 0.f, 0.f};

    for (int kb = 0; kb < DMODEL; kb += 32) {
#pragma unroll
        for (int c = 0; c < 2; ++c) {
            const int chunk = tid + c * 256;
            const int row = chunk >> 2;
            const int col = (chunk & 3) * 8;
            *(f16x8*)(As + row * 40 + col) =
                *(const f16x8*)(A + (size_t)(m0 + row) * DMODEL + kb + col);
            const float* gb = W + (size_t)(n0 + row) * DMODEL + kb + col;
            float4 b0 = *(const float4*)gb;
            float4 b1 = *(const float4*)(gb + 4);
            f16x8 hb = { (f16)b0.x, (f16)b0.y, (f16)b0.z, (f16)b0.w,
                         (f16)b1.x, (f16)b1.y, (f16)b1.z, (f16)b1.w };
            *(f16x8*)(Bs + row * 40 + col) = hb;
        }
        __syncthreads();
        f16x8 af[4], bf[4];
#pragma unroll
        for (int i = 0; i < 4; ++i)
            af[i] = *(const f16x8*)(As + (wm + 16 * i + lr) * 40 + 8 * lg);
#pragma unroll
        for (int j = 0; j < 4; ++j)
            bf[j] = *(const f16x8*)(Bs + (wn + 16 * j + lr) * 40 + 8 * lg);
#pragma unroll
        for (int i = 0; i < 4; ++i)
#pragma unroll
            for (int j = 0; j < 4; ++j)
                acc[i][j] = mfma16(af[i], bf[j], acc[i][j]);
        __syncthreads();
    }

#pragma unroll
    for (int i = 0; i < 4; ++i) {
        const int mbase = m0 + wm + 16 * i + 4 * lg;
#pragma unroll
        for (int j = 0; j < 4; ++j) {
            const int n = n0 + wn + 16 * j + lr;
            const float bn = bias[n];
#pragma unroll
            for (int r = 0; r < 4; ++r) {
                const int m = mbase + r;
                out[(size_t)m * DMODEL + n] = acc[i][j][r] + bn;
            }
        }
    }
}

extern "C" void kernel_launch(void* const* d_in, const int* in_sizes, int n_in,
                              void* d_out, int out_size, void* d_ws, size_t ws_size,
                              hipStream_t stream) {
    const float* q  = (const float*)d_in[0];
    const float* k  = (const float*)d_in[1];
    const float* v  = (const float*)d_in[2];
    const float* Wq = (const float*)d_in[3];
    const float* Wk = (const float*)d_in[4];
    const float* Wv = (const float*)d_in[5];
    const float* Wo = (const float*)d_in[6];
    const float* bo = (const float*)d_in[7];
    float* out = (float*)d_out;

    const size_t per = (size_t)NB * NH * S_TOK * DKH;   // 4,194,304 f16
    f16* qh  = (f16*)d_ws;
    f16* kh  = qh + per;
    f16* vt  = kh + per;
    f16* ctx = vt + per;
    f16* pO  = ctx + per;                                  // 2048 units x 128 x 64 f16 = 32 MB
    float* pL = (float*)(pO + (size_t)2048 * 128 * 64);    // 1 MB

    proj_fused_kernel<<<dim3(64, 4, 3), 256, 0, stream>>>(q, k, v, Wq, Wk, Wv, qh, kh, vt);
    attn_kernel<<<dim3(1024), 256, 0, stream>>>(qh, kh, vt, pO, pL);
    merge_kernel<<<dim3(2048), 256, 0, stream>>>(pO, pL, ctx);
    oproj_kernel<<<dim3(64, 4), 256, 0, stream>>>(ctx, Wo, bo, out);
}

// Round 8
// 134.048 us; speedup vs baseline: 1.0186x; 1.0186x over previous
//
#include <hip/hip_runtime.h>

typedef _Float16 f16;
typedef _Float16 f16x8 __attribute__((ext_vector_type(8)));
typedef _Float16 f16x4 __attribute__((ext_vector_type(4)));
typedef _Float16 f16x2 __attribute__((ext_vector_type(2)));
typedef float f32x4 __attribute__((ext_vector_type(4)));
typedef float f32x16 __attribute__((ext_vector_type(16)));
typedef unsigned int u32x2 __attribute__((ext_vector_type(2)));

#define S_TOK 4096
#define NB 2
#define NH 8
#define DKH 64
#define DMODEL 512

static __device__ __forceinline__ f32x4 mfma16(f16x8 a, f16x8 b, f32x4 c) {
    return __builtin_amdgcn_mfma_f32_16x16x32_f16(a, b, c, 0, 0, 0);
}
static __device__ __forceinline__ f32x16 mfma32(f16x8 a, f16x8 b, f32x16 c) {
    return __builtin_amdgcn_mfma_f32_32x32x16_f16(a, b, c, 0, 0, 0);
}
// async global->LDS, 16B per lane; lds must be wave-uniform base
static __device__ __forceinline__ void gl16(const f16* g, f16* l) {
    __builtin_amdgcn_global_load_lds(
        (const __attribute__((address_space(1))) unsigned int*)g,
        (__attribute__((address_space(3))) unsigned int*)l, 16, 0, 0);
}

// ---------------- fused QKV projection: out = x @ W^T (x:[8192][512] f32, W:[512][512] f32)
// mode 0 = Q (scaled 1/8 * log2(e), [bh][s][dk]); 1 = K; 2 = V ([bh][dk][s] transposed)
__global__ __launch_bounds__(256)
void proj_fused_kernel(const float* __restrict__ qx, const float* __restrict__ kx,
                       const float* __restrict__ vx,
                       const float* __restrict__ Wqp, const float* __restrict__ Wkp,
                       const float* __restrict__ Wvp,
                       f16* __restrict__ qo, f16* __restrict__ ko, f16* __restrict__ vo)
{
    const int mode = blockIdx.z;
    const float* x = (mode == 0) ? qx : (mode == 1) ? kx : vx;
    const float* W = (mode == 0) ? Wqp : (mode == 1) ? Wkp : Wvp;
    f16* out = (mode == 0) ? qo : (mode == 1) ? ko : vo;

    __shared__ f16 As[128 * 40];
    __shared__ f16 Bs[128 * 40];
    const int m0 = blockIdx.x * 128;
    const int n0 = blockIdx.y * 128;
    const int tid = threadIdx.x;
    const int wv = tid >> 6;
    const int lane = tid & 63;
    const int lr = lane & 15, lg = lane >> 4;
    const int wm = (wv >> 1) * 64, wn = (wv & 1) * 64;

    f32x4 acc[4][4];
#pragma unroll
    for (int i = 0; i < 4; ++i)
#pragma unroll
        for (int j = 0; j < 4; ++j) acc[i][j] = f32x4{0.f, 0.f, 0.f, 0.f};

    for (int kb = 0; kb < DMODEL; kb += 32) {
#pragma unroll
        for (int c = 0; c < 2; ++c) {
            const int chunk = tid + c * 256;
            const int row = chunk >> 2;
            const int col = (chunk & 3) * 8;
            const float* ga = x + (size_t)(m0 + row) * DMODEL + kb + col;
            float4 a0 = *(const float4*)ga;
            float4 a1 = *(const float4*)(ga + 4);
            f16x8 ha = { (f16)a0.x, (f16)a0.y, (f16)a0.z, (f16)a0.w,
                         (f16)a1.x, (f16)a1.y, (f16)a1.z, (f16)a1.w };
            *(f16x8*)(As + row * 40 + col) = ha;
            const float* gb = W + (size_t)(n0 + row) * DMODEL + kb + col;
            float4 b0 = *(const float4*)gb;
            float4 b1 = *(const float4*)(gb + 4);
            f16x8 hb = { (f16)b0.x, (f16)b0.y, (f16)b0.z, (f16)b0.w,
                         (f16)b1.x, (f16)b1.y, (f16)b1.z, (f16)b1.w };
            *(f16x8*)(Bs + row * 40 + col) = hb;
        }
        __syncthreads();
        f16x8 af[4], bf[4];
#pragma unroll
        for (int i = 0; i < 4; ++i)
            af[i] = *(const f16x8*)(As + (wm + 16 * i + lr) * 40 + 8 * lg);
#pragma unroll
        for (int j = 0; j < 4; ++j)
            bf[j] = *(const f16x8*)(Bs + (wn + 16 * j + lr) * 40 + 8 * lg);
#pragma unroll
        for (int i = 0; i < 4; ++i)
#pragma unroll
            for (int j = 0; j < 4; ++j)
                acc[i][j] = mfma16(af[i], bf[j], acc[i][j]);
        __syncthreads();
    }

#pragma unroll
    for (int i = 0; i < 4; ++i) {
        const int mbase = m0 + wm + 16 * i + 4 * lg;
#pragma unroll
        for (int j = 0; j < 4; ++j) {
            const int n = n0 + wn + 16 * j + lr;
            const int h = n >> 6, dk = n & 63;
            if (mode == 2) {
                const int b = mbase >> 12;
                const int s = mbase & 4095;
                f16x4 v4;
#pragma unroll
                for (int r = 0; r < 4; ++r) v4[r] = (f16)acc[i][j][r];
                *(f16x4*)(out + ((size_t)(b * NH + h) * DKH + dk) * S_TOK + s) = v4;
            } else {
                const float sc = (mode == 0) ? 0.1803368801111244f : 1.0f;
#pragma unroll
                for (int r = 0; r < 4; ++r) {
                    const int m = mbase + r;
                    const int b = m >> 12, s = m & 4095;
                    out[((size_t)(b * NH + h) * S_TOK + s) * DKH + dk] = (f16)(acc[i][j][r] * sc);
                }
            }
        }
    }
}

// ---------------- causal flash attention, 32x32 MFMA, 4 kv-chunks, permlane P exchange
// 1024 blocks x 4 waves (32 q/wave, QBLK=128). Block (j, cb): (qt=j, chunk cb) then
// (qt=31-j, chunk 3-cb) -> 16-17 steps every block. No P LDS (permlane32_swap).
// launch_bounds(256,2): VGPR headroom — the (256,4) variant spilled (VGPR=64 < ~90 live).
__global__ __launch_bounds__(256, 2)
void attn_kernel(const f16* __restrict__ qh, const f16* __restrict__ kh,
                 const f16* __restrict__ vt, f16* __restrict__ pO, float* __restrict__ pL)
{
    __shared__ f16 Ks[2][64 * 64];   // [kv][dk], granule-XOR swizzled (slot = g ^ (row&7))
    __shared__ f16 Vs[2][64 * 64];   // [dk][kv], granule-XOR swizzled

    const int bid = blockIdx.x;
    const int bh = 2 * (bid & 7) + ((bid >> 3) & 1);   // XCD affinity: 2 heads/XCD
    const int j = (bid >> 4) & 31;
    const int cb = (bid >> 9) & 1;
    const int tid = threadIdx.x, wv = tid >> 6, lane = tid & 63;
    const int l31 = lane & 31, h = lane >> 5;

    const f16* Qp = qh + (size_t)bh * S_TOK * DKH;
    const f16* Kp = kh + (size_t)bh * S_TOK * DKH;
    const f16* Vp = vt + (size_t)bh * DKH * S_TOK;

    // staging: granule gid = tid (rows 0-31) and tid+256 (rows 32-63); slot = tid&7
    const int srow = tid >> 3;            // 0..31
    const int sg = tid & 7;
    const int sgx = sg ^ (srow & 7);      // pre-swizzled global granule (rows +32: same row&7)

    int cur = 0;
    for (int seg = 0; seg < 2; ++seg) {
        const int qt = seg ? (31 - j) : j;
        const int cc = seg ? (3 - cb) : cb;
        const int T = 2 * qt + 2;
        const int tb = (cc * T) >> 2;
        const int te = ((cc + 1) * T) >> 2;
        const int qw = qt * 128 + 32 * wv + l31;
        const int unit = (bh * 32 + qt) * 4 + cc;

        f16x8 aq[4];
#pragma unroll
        for (int s = 0; s < 4; ++s)
            aq[s] = *(const f16x8*)(Qp + (size_t)qw * DKH + 16 * s + 8 * h);

        f32x16 accO0 = {}, accO1 = {};
        float mrow = -1e20f, lrow = 0.f;

        if (te > tb) {
            {   // stage first tile into buf[cur]
                const f16* kp1 = Kp + (size_t)(64 * tb + srow) * DKH + sgx * 8;
                gl16(kp1, &Ks[cur][wv * 512]);
                gl16(kp1 + 32 * DKH, &Ks[cur][2048 + wv * 512]);
                const f16* vp1 = Vp + (size_t)srow * S_TOK + 64 * tb + sgx * 8;
                gl16(vp1, &Vs[cur][wv * 512]);
                gl16(vp1 + (size_t)32 * S_TOK, &Vs[cur][2048 + wv * 512]);
            }
            for (int t = tb; t < te; ++t) {
                __syncthreads();      // stage(t) landed; prior reads of buf[cur^1] done
                if (t + 1 < te) {     // stage next tile into the other buffer
                    const f16* kp1 = Kp + (size_t)(64 * (t + 1) + srow) * DKH + sgx * 8;
                    gl16(kp1, &Ks[cur ^ 1][wv * 512]);
                    gl16(kp1 + 32 * DKH, &Ks[cur ^ 1][2048 + wv * 512]);
                    const f16* vp1 = Vp + (size_t)srow * S_TOK + 64 * (t + 1) + sgx * 8;
                    gl16(vp1, &Vs[cur ^ 1][wv * 512]);
                    gl16(vp1 + (size_t)32 * S_TOK, &Vs[cur ^ 1][2048 + wv * 512]);
                }
                const f16* Kb = &Ks[cur][0];
                const f16* Vb = &Vs[cur][0];

                // S^T = K x Q^T : D[kv = 32*half + (e&3)+8*(e>>2)+4h][q = l31]
                f32x16 accS0 = {}, accS1 = {};
                __builtin_amdgcn_s_setprio(1);
#pragma unroll
                for (int s = 0; s < 4; ++s) {
                    f16x8 ak0 = *(const f16x8*)(Kb + l31 * 64 + ((2 * s + h) ^ (l31 & 7)) * 8);
                    f16x8 ak1 = *(const f16x8*)(Kb + (32 + l31) * 64 + ((2 * s + h) ^ (l31 & 7)) * 8);
                    accS0 = mfma32(ak0, aq[s], accS0);
                    accS1 = mfma32(ak1, aq[s], accS1);
                }
                __builtin_amdgcn_s_setprio(0);

                if (t >= 2 * qt) {   // diagonal tiles: causal mask
#pragma unroll
                    for (int e = 0; e < 16; ++e) {
                        const int kvb = 64 * t + (e & 3) + 8 * (e >> 2) + 4 * h;
                        accS0[e] = (kvb > qw) ? -1e30f : accS0[e];
                        accS1[e] = (kvb + 32 > qw) ? -1e30f : accS1[e];
                    }
                }

                // online softmax max: pairwise tree (depth 5), kv in-lane + xor-32 partner
                float t8[8];
#pragma unroll
                for (int e = 0; e < 8; ++e)
                    t8[e] = fmaxf(fmaxf(accS0[2 * e], accS0[2 * e + 1]),
                                  fmaxf(accS1[2 * e], accS1[2 * e + 1]));
                float t4a = fmaxf(t8[0], t8[1]), t4b = fmaxf(t8[2], t8[3]);
                float t4c = fmaxf(t8[4], t8[5]), t4d = fmaxf(t8[6], t8[7]);
                float tm = fmaxf(fmaxf(t4a, t4b), fmaxf(t4c, t4d));
                tm = fmaxf(tm, __shfl_xor(tm, 32));
                if (!__all(tm <= mrow + 8.f)) {   // defer-max (T13)
                    const float mn = fmaxf(mrow, tm);
                    const float sf = exp2f(mrow - mn);
                    lrow *= sf;
                    accO0 *= sf;  accO1 *= sf;
                    mrow = mn;
                }

                float sg8[8];   // per-g partial sums (tree at the end)
                // half 0 (kv 0..31): exp -> pack -> permlane -> PV s'=0,1
                {
                    unsigned int Xd0[4], Xd1[4];
#pragma unroll
                    for (int g = 0; g < 4; ++g) {
                        float p0 = exp2f(accS0[4 * g + 0] - mrow);
                        float p1 = exp2f(accS0[4 * g + 1] - mrow);
                        float p2 = exp2f(accS0[4 * g + 2] - mrow);
                        float p3 = exp2f(accS0[4 * g + 3] - mrow);
                        sg8[g] = (p0 + p1) + (p2 + p3);
                        union { f16x2 hh; unsigned int u; } a0, a1;
                        a0.hh = f16x2{(f16)p0, (f16)p1};
                        a1.hh = f16x2{(f16)p2, (f16)p3};
                        Xd0[g] = a0.u;  Xd1[g] = a1.u;
                    }
                    __builtin_amdgcn_s_setprio(1);
#pragma unroll
                    for (int sp = 0; sp < 2; ++sp) {
                        u32x2 rA = __builtin_amdgcn_permlane32_swap(Xd0[2 * sp], Xd0[2 * sp + 1], false, false);
                        u32x2 rB = __builtin_amdgcn_permlane32_swap(Xd1[2 * sp], Xd1[2 * sp + 1], false, false);
                        union { unsigned int u[4]; f16x8 v; } F;
                        F.u[0] = rA[0]; F.u[1] = rB[0]; F.u[2] = rA[1]; F.u[3] = rB[1];
                        f16x8 av0 = *(const f16x8*)(Vb + l31 * 64 + ((2 * sp + h) ^ (l31 & 7)) * 8);
                        f16x8 av1 = *(const f16x8*)(Vb + (32 + l31) * 64 + ((2 * sp + h) ^ (l31 & 7)) * 8);
                        accO0 = mfma32(av0, F.v, accO0);
                        accO1 = mfma32(av1, F.v, accO1);
                    }
                    __builtin_amdgcn_s_setprio(0);
                }
                // half 1 (kv 32..63): s'=2,3
                {
                    unsigned int Xd0[4], Xd1[4];
#pragma unroll
                    for (int g = 0; g < 4; ++g) {
                        float p0 = exp2f(accS1[4 * g + 0] - mrow);
                        float p1 = exp2f(accS1[4 * g + 1] - mrow);
                        float p2 = exp2f(accS1[4 * g + 2] - mrow);
                        float p3 = exp2f(accS1[4 * g + 3] - mrow);
                        sg8[4 + g] = (p0 + p1) + (p2 + p3);
                        union { f16x2 hh; unsigned int u; } a0, a1;
                        a0.hh = f16x2{(f16)p0, (f16)p1};
                        a1.hh = f16x2{(f16)p2, (f16)p3};
                        Xd0[g] = a0.u;  Xd1[g] = a1.u;
                    }
                    __builtin_amdgcn_s_setprio(1);
#pragma unroll
                    for (int sp = 0; sp < 2; ++sp) {
                        const int spp = 2 + sp;
                        u32x2 rA = __builtin_amdgcn_permlane32_swap(Xd0[2 * sp], Xd0[2 * sp + 1], false, false);
                        u32x2 rB = __builtin_amdgcn_permlane32_swap(Xd1[2 * sp], Xd1[2 * sp + 1], false, false);
                        union { unsigned int u[4]; f16x8 v; } F;
                        F.u[0] = rA[0]; F.u[1] = rB[0]; F.u[2] = rA[1]; F.u[3] = rB[1];
                        f16x8 av0 = *(const f16x8*)(Vb + l31 * 64 + ((2 * spp + h) ^ (l31 & 7)) * 8);
                        f16x8 av1 = *(const f16x8*)(Vb + (32 + l31) * 64 + ((2 * spp + h) ^ (l31 & 7)) * 8);
                        accO0 = mfma32(av0, F.v, accO0);
                        accO1 = mfma32(av1, F.v, accO1);
                    }
                    __builtin_amdgcn_s_setprio(0);
                }
                // sum tree (depth 3) + cross-half
                float s4a = sg8[0] + sg8[1], s4b = sg8[2] + sg8[3];
                float s4c = sg8[4] + sg8[5], s4d = sg8[6] + sg8[7];
                float ts = (s4a + s4b) + (s4c + s4d);
                ts += __shfl_xor(ts, 32);
                lrow += ts;
                cur ^= 1;
            }
        }

        // write partial: O_norm f16 + L = m + log2(l)
        const float invl = (lrow > 0.f) ? (1.f / lrow) : 0.f;
        f16* Ob = pO + ((size_t)unit * 128 + (32 * wv + l31)) * DKH;
#pragma unroll
        for (int g = 0; g < 4; ++g) {
            f16x4 o0, o1;
#pragma unroll
            for (int r = 0; r < 4; ++r) {
                o0[r] = (f16)(accO0[4 * g + r] * invl);
                o1[r] = (f16)(accO1[4 * g + r] * invl);
            }
            *(f16x4*)(Ob + 8 * g + 4 * h) = o0;
            *(f16x4*)(Ob + 32 + 8 * g + 4 * h) = o1;
        }
        if (h == 0)
            pL[unit * 128 + 32 * wv + l31] =
                (lrow > 0.f) ? (mrow + __log2f(lrow)) : -1e30f;
    }
}

// ---------------- merge 4 kv-chunk partials per q-row -> ctx f16
__global__ __launch_bounds__(256)
void merge_kernel(const f16* __restrict__ pO, const float* __restrict__ pL,
                  f16* __restrict__ ctx)
{
    const int tid = threadIdx.x;
    const int R = blockIdx.x * 32 + (tid >> 3);   // row id 0..65535
    const int dkg = tid & 7;
    const int bh = R >> 12, q = R & 4095;
    const int qt = q >> 7, qi = q & 127;
    const int ub = (bh * 32 + qt) * 4;

    float L[4];
#pragma unroll
    for (int c = 0; c < 4; ++c) L[c] = pL[(ub + c) * 128 + qi];
    float Lm = fmaxf(fmaxf(L[0], L[1]), fmaxf(L[2], L[3]));
    float w[4], wsum = 0.f;
#pragma unroll
    for (int c = 0; c < 4; ++c) { w[c] = exp2f(L[c] - Lm); wsum += w[c]; }
    const float inv = 1.f / wsum;

    float o[8];
#pragma unroll
    for (int i = 0; i < 8; ++i) o[i] = 0.f;
#pragma unroll
    for (int c = 0; c < 4; ++c) {
        f16x8 a = *(const f16x8*)(pO + ((size_t)(ub + c) * 128 + qi) * DKH + dkg * 8);
#pragma unroll
        for (int i = 0; i < 8; ++i) o[i] += w[c] * (float)a[i];
    }
    f16x8 ov;
#pragma unroll
    for (int i = 0; i < 8; ++i) ov[i] = (f16)(o[i] * inv);

    const int bb = bh >> 3, hh = bh & 7;
    *(f16x8*)(ctx + ((size_t)(bb * S_TOK + q)) * DMODEL + hh * DKH + dkg * 8) = ov;
}

// ---------------- output projection: out = ctx(f16) @ W_o^T + b_o, fp32 out
__global__ __launch_bounds__(256)
void oproj_kernel(const f16* __restrict__ A, const float* __restrict__ W,
                  const float* __restrict__ bias, float* __restrict__ out)
{
    __shared__ f16 As[128 * 40];
    __shared__ f16 Bs[128 * 40];
    const int m0 = blockIdx.x * 128;
    const int n0 = blockIdx.y * 128;
    const int tid = threadIdx.x;
    const int wv = tid >> 6;
    const int lane = tid & 63;
    const int lr = lane & 15, lg = lane >> 4;
    const int wm = (wv >> 1) * 64, wn = (wv & 1) * 64;

    f32x4 acc[4][4];
#pragma unroll
    for (int i = 0; i < 4; ++i)
#pragma unroll
        for (int j = 0; j < 4; ++j) acc[i][j] = f32x4{0.f, 0.f, 0.f, 0.f};

    for (int kb = 0; kb < DMODEL; kb += 32) {
#pragma unroll
        for (int c = 0; c < 2; ++c) {
            const int chunk = tid + c * 256;
            const int row = chunk >> 2;
            const int col = (chunk & 3) * 8;
            *(f16x8*)(As + row * 40 + col) =
                *(const f16x8*)(A + (size_t)(m0 + row) * DMODEL + kb + col);
            const float* gb = W + (size_t)(n0 + row) * DMODEL + kb + col;
            float4 b0 = *(const float4*)gb;
            float4 b1 = *(const float4*)(gb + 4);
            f16x8 hb = { (f16)b0.x, (f16)b0.y, (f16)b0.z, (f16)b0.w,
                         (f16)b1.x, (f16)b1.y, (f16)b1.z, (f16)b1.w };
            *(f16x8*)(Bs + row * 40 + col) = hb;
        }
        __syncthreads();
        f16x8 af[4], bf[4];
#pragma unroll
        for (int i = 0; i < 4; ++i)
            af[i] = *(const f16x8*)(As + (wm + 16 * i + lr) * 40 + 8 * lg);
#pragma unroll
        for (int j = 0; j < 4; ++j)
            bf[j] = *(const f16x8*)(Bs + (wn + 16 * j + lr) * 40 + 8 * lg);
#pragma unroll
        for (int i = 0; i < 4; ++i)
#pragma unroll
            for (int j = 0; j < 4; ++j)
                acc[i][j] = mfma16(af[i], bf[j], acc[i][j]);
        __syncthreads();
    }

#pragma unroll
    for (int i = 0; i < 4; ++i) {
        const int mbase = m0 + wm + 16 * i + 4 * lg;
#pragma unroll
        for (int j = 0; j < 4; ++j) {
            const int n = n0 + wn + 16 * j + lr;
            const float bn = bias[n];
#pragma unroll
            for (int r = 0; r < 4; ++r) {
                const int m = mbase + r;
                out[(size_t)m * DMODEL + n] = acc[i][j][r] + bn;
            }
        }
    }
}

extern "C" void kernel_launch(void* const* d_in, const int* in_sizes, int n_in,
                              void* d_out, int out_size, void* d_ws, size_t ws_size,
                              hipStream_t stream) {
    const float* q  = (const float*)d_in[0];
    const float* k  = (const float*)d_in[1];
    const float* v  = (const float*)d_in[2];
    const float* Wq = (const float*)d_in[3];
    const float* Wk = (const float*)d_in[4];
    const float* Wv = (const float*)d_in[5];
    const float* Wo = (const float*)d_in[6];
    const float* bo = (const float*)d_in[7];
    float* out = (float*)d_out;

    const size_t per = (size_t)NB * NH * S_TOK * DKH;   // 4,194,304 f16
    f16* qh  = (f16*)d_ws;
    f16* kh  = qh + per;
    f16* vt  = kh + per;
    f16* ctx = vt + per;
    f16* pO  = ctx + per;                                  // 2048 units x 128 x 64 f16 = 32 MB
    float* pL = (float*)(pO + (size_t)2048 * 128 * 64);    // 1 MB

    proj_fused_kernel<<<dim3(64, 4, 3), 256, 0, stream>>>(q, k, v, Wq, Wk, Wv, qh, kh, vt);
    attn_kernel<<<dim3(1024), 256, 0, stream>>>(qh, kh, vt, pO, pL);
    merge_kernel<<<dim3(2048), 256, 0, stream>>>(pO, pL, ctx);
    oproj_kernel<<<dim3(64, 4), 256, 0, stream>>>(ctx, Wo, bo, out);
}

// Round 9
// 131.700 us; speedup vs baseline: 1.0368x; 1.0178x over previous
//
#include <hip/hip_runtime.h>

typedef _Float16 f16;
typedef _Float16 f16x8 __attribute__((ext_vector_type(8)));
typedef _Float16 f16x4 __attribute__((ext_vector_type(4)));
typedef _Float16 f16x2 __attribute__((ext_vector_type(2)));
typedef float f32x4 __attribute__((ext_vector_type(4)));
typedef float f32x16 __attribute__((ext_vector_type(16)));
typedef unsigned int u32x2 __attribute__((ext_vector_type(2)));

#define S_TOK 4096
#define NB 2
#define NH 8
#define DKH 64
#define DMODEL 512

static __device__ __forceinline__ f32x4 mfma16(f16x8 a, f16x8 b, f32x4 c) {
    return __builtin_amdgcn_mfma_f32_16x16x32_f16(a, b, c, 0, 0, 0);
}
static __device__ __forceinline__ f32x16 mfma32(f16x8 a, f16x8 b, f32x16 c) {
    return __builtin_amdgcn_mfma_f32_32x32x16_f16(a, b, c, 0, 0, 0);
}
// async global->LDS, 16B per lane; lds must be wave-uniform base
static __device__ __forceinline__ void gl16(const f16* g, f16* l) {
    __builtin_amdgcn_global_load_lds(
        (const __attribute__((address_space(1))) unsigned int*)g,
        (__attribute__((address_space(3))) unsigned int*)l, 16, 0, 0);
}

// ---------------- fused QKV projection: out = x @ W^T (x:[8192][512] f32, W:[512][512] f32)
// mode 0 = Q (scaled 1/8 * log2(e), [bh][s][dk]); 1 = K; 2 = V ([bh][dk][s] transposed)
__global__ __launch_bounds__(256)
void proj_fused_kernel(const float* __restrict__ qx, const float* __restrict__ kx,
                       const float* __restrict__ vx,
                       const float* __restrict__ Wqp, const float* __restrict__ Wkp,
                       const float* __restrict__ Wvp,
                       f16* __restrict__ qo, f16* __restrict__ ko, f16* __restrict__ vo)
{
    const int mode = blockIdx.z;
    const float* x = (mode == 0) ? qx : (mode == 1) ? kx : vx;
    const float* W = (mode == 0) ? Wqp : (mode == 1) ? Wkp : Wvp;
    f16* out = (mode == 0) ? qo : (mode == 1) ? ko : vo;

    __shared__ f16 As[128 * 40];
    __shared__ f16 Bs[128 * 40];
    const int m0 = blockIdx.x * 128;
    const int n0 = blockIdx.y * 128;
    const int tid = threadIdx.x;
    const int wv = tid >> 6;
    const int lane = tid & 63;
    const int lr = lane & 15, lg = lane >> 4;
    const int wm = (wv >> 1) * 64, wn = (wv & 1) * 64;

    f32x4 acc[4][4];
#pragma unroll
    for (int i = 0; i < 4; ++i)
#pragma unroll
        for (int j = 0; j < 4; ++j) acc[i][j] = f32x4{0.f, 0.f, 0.f, 0.f};

    for (int kb = 0; kb < DMODEL; kb += 32) {
#pragma unroll
        for (int c = 0; c < 2; ++c) {
            const int chunk = tid + c * 256;
            const int row = chunk >> 2;
            const int col = (chunk & 3) * 8;
            const float* ga = x + (size_t)(m0 + row) * DMODEL + kb + col;
            float4 a0 = *(const float4*)ga;
            float4 a1 = *(const float4*)(ga + 4);
            f16x8 ha = { (f16)a0.x, (f16)a0.y, (f16)a0.z, (f16)a0.w,
                         (f16)a1.x, (f16)a1.y, (f16)a1.z, (f16)a1.w };
            *(f16x8*)(As + row * 40 + col) = ha;
            const float* gb = W + (size_t)(n0 + row) * DMODEL + kb + col;
            float4 b0 = *(const float4*)gb;
            float4 b1 = *(const float4*)(gb + 4);
            f16x8 hb = { (f16)b0.x, (f16)b0.y, (f16)b0.z, (f16)b0.w,
                         (f16)b1.x, (f16)b1.y, (f16)b1.z, (f16)b1.w };
            *(f16x8*)(Bs + row * 40 + col) = hb;
        }
        __syncthreads();
        f16x8 af[4], bf[4];
#pragma unroll
        for (int i = 0; i < 4; ++i)
            af[i] = *(const f16x8*)(As + (wm + 16 * i + lr) * 40 + 8 * lg);
#pragma unroll
        for (int j = 0; j < 4; ++j)
            bf[j] = *(const f16x8*)(Bs + (wn + 16 * j + lr) * 40 + 8 * lg);
#pragma unroll
        for (int i = 0; i < 4; ++i)
#pragma unroll
            for (int j = 0; j < 4; ++j)
                acc[i][j] = mfma16(af[i], bf[j], acc[i][j]);
        __syncthreads();
    }

#pragma unroll
    for (int i = 0; i < 4; ++i) {
        const int mbase = m0 + wm + 16 * i + 4 * lg;
#pragma unroll
        for (int j = 0; j < 4; ++j) {
            const int n = n0 + wn + 16 * j + lr;
            const int h = n >> 6, dk = n & 63;
            if (mode == 2) {
                const int b = mbase >> 12;
                const int s = mbase & 4095;
                f16x4 v4;
#pragma unroll
                for (int r = 0; r < 4; ++r) v4[r] = (f16)acc[i][j][r];
                *(f16x4*)(out + ((size_t)(b * NH + h) * DKH + dk) * S_TOK + s) = v4;
            } else {
                const float sc = (mode == 0) ? 0.1803368801111244f : 1.0f;
#pragma unroll
                for (int r = 0; r < 4; ++r) {
                    const int m = mbase + r;
                    const int b = m >> 12, s = m & 4095;
                    out[((size_t)(b * NH + h) * S_TOK + s) * DKH + dk] = (f16)(acc[i][j][r] * sc);
                }
            }
        }
    }
}

// ---------------- causal flash attention, 32x32 MFMA, 4 kv-chunks, permlane P exchange
// 1024 blocks x 4 waves (32 q/wave, QBLK=128). Half-step processing (kv 0..31 fully,
// then 32..63) keeps live regs ~105 <= 128 so (256,4) gives 4 blocks/CU WITHOUT spill.
// Swizzle swz(r)=(r&7)^(((r>>3)&3)<<1) breaks the 4-way bank alias of rows 8 apart.
__global__ __launch_bounds__(256, 4)
void attn_kernel(const f16* __restrict__ qh, const f16* __restrict__ kh,
                 const f16* __restrict__ vt, f16* __restrict__ pO, float* __restrict__ pL)
{
    __shared__ f16 Ks[2][64 * 64];   // [kv][dk], granule slot = g ^ swz(row)
    __shared__ f16 Vs[2][64 * 64];   // [dk][kv]

    const int bid = blockIdx.x;
    const int bh = 2 * (bid & 7) + ((bid >> 3) & 1);   // XCD affinity: 2 heads/XCD
    const int j = (bid >> 4) & 31;
    const int cb = (bid >> 9) & 1;
    const int tid = threadIdx.x, wv = tid >> 6, lane = tid & 63;
    const int l31 = lane & 31, h = lane >> 5;
    const int swzl = (l31 & 7) ^ (((l31 >> 3) & 3) << 1);

    const f16* Qp = qh + (size_t)bh * S_TOK * DKH;
    const f16* Kp = kh + (size_t)bh * S_TOK * DKH;
    const f16* Vp = vt + (size_t)bh * DKH * S_TOK;

    // staging: rows srow & srow+32; LDS slot sg holds global granule sg^swz(row)
    const int srow = tid >> 3;            // 0..31
    const int sg = tid & 7;
    const int sgx = sg ^ ((srow & 7) ^ (((srow >> 3) & 3) << 1));  // same for row+32

    int cur = 0;
    for (int seg = 0; seg < 2; ++seg) {
        const int qt = seg ? (31 - j) : j;
        const int cc = seg ? (3 - cb) : cb;
        const int T = 2 * qt + 2;
        const int tb = (cc * T) >> 2;
        const int te = ((cc + 1) * T) >> 2;
        const int qw = qt * 128 + 32 * wv + l31;
        const int unit = (bh * 32 + qt) * 4 + cc;

        f16x8 aq[4];
#pragma unroll
        for (int s = 0; s < 4; ++s)
            aq[s] = *(const f16x8*)(Qp + (size_t)qw * DKH + 16 * s + 8 * h);

        f32x16 accO0 = {}, accO1 = {};
        float mrow = -1e20f, lrow = 0.f;

        if (te > tb) {
            {   // stage first tile into buf[cur]
                const f16* kp1 = Kp + (size_t)(64 * tb + srow) * DKH + sgx * 8;
                gl16(kp1, &Ks[cur][wv * 512]);
                gl16(kp1 + 32 * DKH, &Ks[cur][2048 + wv * 512]);
                const f16* vp1 = Vp + (size_t)srow * S_TOK + 64 * tb + sgx * 8;
                gl16(vp1, &Vs[cur][wv * 512]);
                gl16(vp1 + (size_t)32 * S_TOK, &Vs[cur][2048 + wv * 512]);
            }
            for (int t = tb; t < te; ++t) {
                __syncthreads();      // stage(t) landed; prior reads of buf[cur^1] done
                if (t + 1 < te) {     // stage next tile into the other buffer
                    const f16* kp1 = Kp + (size_t)(64 * (t + 1) + srow) * DKH + sgx * 8;
                    gl16(kp1, &Ks[cur ^ 1][wv * 512]);
                    gl16(kp1 + 32 * DKH, &Ks[cur ^ 1][2048 + wv * 512]);
                    const f16* vp1 = Vp + (size_t)srow * S_TOK + 64 * (t + 1) + sgx * 8;
                    gl16(vp1, &Vs[cur ^ 1][wv * 512]);
                    gl16(vp1 + (size_t)32 * S_TOK, &Vs[cur ^ 1][2048 + wv * 512]);
                }
                const f16* Kb = &Ks[cur][0];
                const f16* Vb = &Vs[cur][0];
                const bool diag = (t >= 2 * qt);

#pragma unroll
                for (int half = 0; half < 2; ++half) {
                    // QK^T for this 32-kv half: D[kv = 64t+32*half+(e&3)+8*(e>>2)+4h][q]
                    f32x16 accS = {};
                    __builtin_amdgcn_s_setprio(1);
#pragma unroll
                    for (int s = 0; s < 4; ++s) {
                        f16x8 ak = *(const f16x8*)(Kb + (32 * half + l31) * 64 +
                                                   ((2 * s + h) ^ swzl) * 8);
                        accS = mfma32(ak, aq[s], accS);
                    }
                    __builtin_amdgcn_s_setprio(0);

                    if (diag) {
#pragma unroll
                        for (int e = 0; e < 16; ++e) {
                            const int kvb = 64 * t + 32 * half + (e & 3) + 8 * (e >> 2) + 4 * h;
                            accS[e] = (kvb > qw) ? -1e30f : accS[e];
                        }
                    }

                    // max tree over 16 in-lane + partner half (xor 32)
                    float m8a = fmaxf(fmaxf(accS[0], accS[1]), fmaxf(accS[2], accS[3]));
                    float m8b = fmaxf(fmaxf(accS[4], accS[5]), fmaxf(accS[6], accS[7]));
                    float m8c = fmaxf(fmaxf(accS[8], accS[9]), fmaxf(accS[10], accS[11]));
                    float m8d = fmaxf(fmaxf(accS[12], accS[13]), fmaxf(accS[14], accS[15]));
                    float tm = fmaxf(fmaxf(m8a, m8b), fmaxf(m8c, m8d));
                    tm = fmaxf(tm, __shfl_xor(tm, 32));
                    if (!__all(tm <= mrow + 8.f)) {   // defer-max (T13)
                        const float mn = fmaxf(mrow, tm);
                        const float sf = exp2f(mrow - mn);
                        lrow *= sf;
                        accO0 *= sf;  accO1 *= sf;
                        mrow = mn;
                    }

                    // exp -> pack -> permlane -> PV for this half
                    unsigned int Xd0[4], Xd1[4];
                    float ts4[4];
#pragma unroll
                    for (int g = 0; g < 4; ++g) {
                        float p0 = exp2f(accS[4 * g + 0] - mrow);
                        float p1 = exp2f(accS[4 * g + 1] - mrow);
                        float p2 = exp2f(accS[4 * g + 2] - mrow);
                        float p3 = exp2f(accS[4 * g + 3] - mrow);
                        ts4[g] = (p0 + p1) + (p2 + p3);
                        union { f16x2 hh; unsigned int u; } a0, a1;
                        a0.hh = f16x2{(f16)p0, (f16)p1};
                        a1.hh = f16x2{(f16)p2, (f16)p3};
                        Xd0[g] = a0.u;  Xd1[g] = a1.u;
                    }
                    float ts = (ts4[0] + ts4[1]) + (ts4[2] + ts4[3]);
                    ts += __shfl_xor(ts, 32);
                    lrow += ts;

                    __builtin_amdgcn_s_setprio(1);
#pragma unroll
                    for (int sp = 0; sp < 2; ++sp) {
                        const int spp = 2 * half + sp;   // kv granule pair index
                        u32x2 rA = __builtin_amdgcn_permlane32_swap(Xd0[2 * sp], Xd0[2 * sp + 1], false, false);
                        u32x2 rB = __builtin_amdgcn_permlane32_swap(Xd1[2 * sp], Xd1[2 * sp + 1], false, false);
                        union { unsigned int u[4]; f16x8 v; } F;
                        F.u[0] = rA[0]; F.u[1] = rB[0]; F.u[2] = rA[1]; F.u[3] = rB[1];
                        f16x8 av0 = *(const f16x8*)(Vb + l31 * 64 + ((2 * spp + h) ^ swzl) * 8);
                        f16x8 av1 = *(const f16x8*)(Vb + (32 + l31) * 64 + ((2 * spp + h) ^ swzl) * 8);
                        accO0 = mfma32(av0, F.v, accO0);
                        accO1 = mfma32(av1, F.v, accO1);
                    }
                    __builtin_amdgcn_s_setprio(0);
                }
                cur ^= 1;
            }
        }

        // write partial: O_norm f16 + L = m + log2(l)
        const float invl = (lrow > 0.f) ? (1.f / lrow) : 0.f;
        f16* Ob = pO + ((size_t)unit * 128 + (32 * wv + l31)) * DKH;
#pragma unroll
        for (int g = 0; g < 4; ++g) {
            f16x4 o0, o1;
#pragma unroll
            for (int r = 0; r < 4; ++r) {
                o0[r] = (f16)(accO0[4 * g + r] * invl);
                o1[r] = (f16)(accO1[4 * g + r] * invl);
            }
            *(f16x4*)(Ob + 8 * g + 4 * h) = o0;
            *(f16x4*)(Ob + 32 + 8 * g + 4 * h) = o1;
        }
        if (h == 0)
            pL[unit * 128 + 32 * wv + l31] =
                (lrow > 0.f) ? (mrow + __log2f(lrow)) : -1e30f;
    }
}

// ---------------- merge 4 kv-chunk partials per q-row -> ctx f16
__global__ __launch_bounds__(256)
void merge_kernel(const f16* __restrict__ pO, const float* __restrict__ pL,
                  f16* __restrict__ ctx)
{
    const int tid = threadIdx.x;
    const int R = blockIdx.x * 32 + (tid >> 3);   // row id 0..65535
    const int dkg = tid & 7;
    const int bh = R >> 12, q = R & 4095;
    const int qt = q >> 7, qi = q & 127;
    const int ub = (bh * 32 + qt) * 4;

    float L[4];
#pragma unroll
    for (int c = 0; c < 4; ++c) L[c] = pL[(ub + c) * 128 + qi];
    float Lm = fmaxf(fmaxf(L[0], L[1]), fmaxf(L[2], L[3]));
    float w[4], wsum = 0.f;
#pragma unroll
    for (int c = 0; c < 4; ++c) { w[c] = exp2f(L[c] - Lm); wsum += w[c]; }
    const float inv = 1.f / wsum;

    float o[8];
#pragma unroll
    for (int i = 0; i < 8; ++i) o[i] = 0.f;
#pragma unroll
    for (int c = 0; c < 4; ++c) {
        f16x8 a = *(const f16x8*)(pO + ((size_t)(ub + c) * 128 + qi) * DKH + dkg * 8);
#pragma unroll
        for (int i = 0; i < 8; ++i) o[i] += w[c] * (float)a[i];
    }
    f16x8 ov;
#pragma unroll
    for (int i = 0; i < 8; ++i) ov[i] = (f16)(o[i] * inv);

    const int bb = bh >> 3, hh = bh & 7;
    *(f16x8*)(ctx + ((size_t)(bb * S_TOK + q)) * DMODEL + hh * DKH + dkg * 8) = ov;
}

// ---------------- output projection: out = ctx(f16) @ W_o^T + b_o, fp32 out
__global__ __launch_bounds__(256)
void oproj_kernel(const f16* __restrict__ A, const float* __restrict__ W,
                  const float* __restrict__ bias, float* __restrict__ out)
{
    __shared__ f16 As[128 * 40];
    __shared__ f16 Bs[128 * 40];
    const int m0 = blockIdx.x * 128;
    const int n0 = blockIdx.y * 128;
    const int tid = threadIdx.x;
    const int wv = tid >> 6;
    const int lane = tid & 63;
    const int lr = lane & 15, lg = lane >> 4;
    const int wm = (wv >> 1) * 64, wn = (wv & 1) * 64;

    f32x4 acc[4][4];
#pragma unroll
    for (int i = 0; i < 4; ++i)
#pragma unroll
        for (int j = 0; j < 4; ++j) acc[i][j] = f32x4{0.f, 0.f, 0.f, 0.f};

    for (int kb = 0; kb < DMODEL; kb += 32) {
#pragma unroll
        for (int c = 0; c < 2; ++c) {
            const int chunk = tid + c * 256;
            const int row = chunk >> 2;
            const int col = (chunk & 3) * 8;
            *(f16x8*)(As + row * 40 + col) =
                *(const f16x8*)(A + (size_t)(m0 + row) * DMODEL + kb + col);
            const float* gb = W + (size_t)(n0 + row) * DMODEL + kb + col;
            float4 b0 = *(const float4*)gb;
            float4 b1 = *(const float4*)(gb + 4);
            f16x8 hb = { (f16)b0.x, (f16)b0.y, (f16)b0.z, (f16)b0.w,
                         (f16)b1.x, (f16)b1.y, (f16)b1.z, (f16)b1.w };
            *(f16x8*)(Bs + row * 40 + col) = hb;
        }
        __syncthreads();
        f16x8 af[4], bf[4];
#pragma unroll
        for (int i = 0; i < 4; ++i)
            af[i] = *(const f16x8*)(As + (wm + 16 * i + lr) * 40 + 8 * lg);
#pragma unroll
        for (int j = 0; j < 4; ++j)
            bf[j] = *(const f16x8*)(Bs + (wn + 16 * j + lr) * 40 + 8 * lg);
#pragma unroll
        for (int i = 0; i < 4; ++i)
#pragma unroll
            for (int j = 0; j < 4; ++j)
                acc[i][j] = mfma16(af[i], bf[j], acc[i][j]);
        __syncthreads();
    }

#pragma unroll
    for (int i = 0; i < 4; ++i) {
        const int mbase = m0 + wm + 16 * i + 4 * lg;
#pragma unroll
        for (int j = 0; j < 4; ++j) {
            const int n = n0 + wn + 16 * j + lr;
            const float bn = bias[n];
#pragma unroll
            for (int r = 0; r < 4; ++r) {
                const int m = mbase + r;
                out[(size_t)m * DMODEL + n] = acc[i][j][r] + bn;
            }
        }
    }
}

extern "C" void kernel_launch(void* const* d_in, const int* in_sizes, int n_in,
                              void* d_out, int out_size, void* d_ws, size_t ws_size,
                              hipStream_t stream) {
    const float* q  = (const float*)d_in[0];
    const float* k  = (const float*)d_in[1];
    const float* v  = (const float*)d_in[2];
    const float* Wq = (const float*)d_in[3];
    const float* Wk = (const float*)d_in[4];
    const float* Wv = (const float*)d_in[5];
    const float* Wo = (const float*)d_in[6];
    const float* bo = (const float*)d_in[7];
    float* out = (float*)d_out;

    const size_t per = (size_t)NB * NH * S_TOK * DKH;   // 4,194,304 f16
    f16* qh  = (f16*)d_ws;
    f16* kh  = qh + per;
    f16* vt  = kh + per;
    f16* ctx = vt + per;
    f16* pO  = ctx + per;                                  // 2048 units x 128 x 64 f16 = 32 MB
    float* pL = (float*)(pO + (size_t)2048 * 128 * 64);    // 1 MB

    proj_fused_kernel<<<dim3(64, 4, 3), 256, 0, stream>>>(q, k, v, Wq, Wk, Wv, qh, kh, vt);
    attn_kernel<<<dim3(1024), 256, 0, stream>>>(qh, kh, vt, pO, pL);
    merge_kernel<<<dim3(2048), 256, 0, stream>>>(pO, pL, ctx);
    oproj_kernel<<<dim3(64, 4), 256, 0, stream>>>(ctx, Wo, bo, out);
}